// Round 14
// baseline (3780.482 us; speedup 1.0000x reference)
//
#include <hip/hip_runtime.h>
#include <hip/hip_bf16.h>
#include <math.h>

#define NB 64
#define NT 512
#define NDIN 256
#define NH 1024
#define NG 4096
#define NDOUT 256

// 256 blocks: ALL do z (4 h-cols, 8-wave splitK) AND proj (1 tile x K-quarter);
// blocks [0,32) also outred (threads 384-511). Dataflow sync (no global barrier
// in steady state). All tail loads prefetched inside the z load window; proj
// MFMA folded before the reduce sync; post-sync phase runs gate | proj-reduce |
// outred on disjoint thread groups. Tail = XMFMA only.
#define GRIDN 256
#define LDSB 122880        // 80K Wz + 32K red(z) + 8K red2(proj)
#define HSTEP 131072       // shorts per h time-slab: [v(2)][ku(32)][mb(4)][512]

typedef __attribute__((ext_vector_type(8))) short short8;
typedef __attribute__((ext_vector_type(4))) float float4v;
typedef __attribute__((ext_vector_type(2))) unsigned uint2v;

__device__ __forceinline__ float sigf(float v) { return 1.0f / (1.0f + expf(-v)); }

__device__ __forceinline__ unsigned short bf_hi(float v, float* back) {
    __hip_bfloat16 b = __float2bfloat16(v);
    *back = __bfloat162float(b);
    union { __hip_bfloat16 b; unsigned short u; } cv; cv.b = b;
    return cv.u;
}

// ---- device-coherent (LLC) helpers ----
#define LD4(o0,o1,o2,o3,p0,p1,p2,p3)                                             \
  asm volatile("global_load_dwordx4 %0, %4, off sc0 sc1\n\t"                     \
               "global_load_dwordx4 %1, %5, off sc0 sc1\n\t"                     \
               "global_load_dwordx4 %2, %6, off sc0 sc1\n\t"                     \
               "global_load_dwordx4 %3, %7, off sc0 sc1\n\t"                     \
               "s_waitcnt vmcnt(0)"                                              \
               : "=&v"(o0),"=&v"(o1),"=&v"(o2),"=&v"(o3)                         \
               : "v"(p0),"v"(p1),"v"(p2),"v"(p3) : "memory")

// cached async load, completion via later waits
#define GLD(dst, p)                                                              \
  asm volatile("global_load_dwordx4 %0, %1, off" : "=&v"(dst) : "v"(p) : "memory")
// LLC-coherent async load, issue-only (drained by later vmcnt(0))
#define SCLD(dst, p)                                                             \
  asm volatile("global_load_dwordx4 %0, %1, off sc0 sc1" : "=&v"(dst) : "v"(p) : "memory")

__device__ __forceinline__ void sc_store_dword(float* p, float v) {
    asm volatile("global_store_dword %0, %1, off sc0 sc1" :: "v"(p), "v"(v) : "memory");
}
__device__ __forceinline__ void sc_store_dwordx2(unsigned short* p, uint2v v) {
    asm volatile("global_store_dwordx2 %0, %1, off sc0 sc1" :: "v"(p), "v"(v) : "memory");
}

// flags: one per block, 16B stride. Flag value t+1 => this block's h(t+1)
// stores AND all its stores from iterations <= t have drained to the LLC.
__device__ __forceinline__ void flag_arrive(unsigned* bar, int bid, int t) {
    asm volatile("s_waitcnt vmcnt(0)" ::: "memory");   // drain ALL own sc-stores
    __syncthreads();
    if (threadIdx.x == 0)
        __hip_atomic_store(bar + (unsigned)bid * 4, (unsigned)(t + 1),
                           __ATOMIC_RELAXED, __HIP_MEMORY_SCOPE_AGENT);
}

// full wait (tail iterations): wave 0 polls all 256 flags >= tgt
__device__ __forceinline__ void wait_full(unsigned* bar, int tgt) {
    if (threadIdx.x < 64) {
        unsigned* f = bar + threadIdx.x * 4;
        for (;;) {
            unsigned v0 = __hip_atomic_load(f,       __ATOMIC_RELAXED, __HIP_MEMORY_SCOPE_AGENT);
            unsigned v1 = __hip_atomic_load(f + 256, __ATOMIC_RELAXED, __HIP_MEMORY_SCOPE_AGENT);
            unsigned v2 = __hip_atomic_load(f + 512, __ATOMIC_RELAXED, __HIP_MEMORY_SCOPE_AGENT);
            unsigned v3 = __hip_atomic_load(f + 768, __ATOMIC_RELAXED, __HIP_MEMORY_SCOPE_AGENT);
            unsigned mn = min(min(v0, v1), min(v2, v3));
            if (__all(mn >= (unsigned)tgt)) break;
        }
    }
    __syncthreads();
}

__global__ void zero_kernel(float* __restrict__ p, int n) {
    int i = blockIdx.x * 256 + threadIdx.x;
    if (i < n) p[i] = 0.0f;
}

// W (= [Wx;Wh], 1280 x 4096) -> per-block LDS image:
// [jb(256)][ku(40)][plane(2)][lane(64)][j(8)]  (80 KB per jb, contiguous)
__global__ void packWz_kernel(const float* __restrict__ Wx, const float* __restrict__ Wh,
                              unsigned short* __restrict__ Wzf) {
    int e = blockIdx.x * 256 + threadIdx.x;
    if (e >= 1280 * 4096) return;
    int k = e >> 12, col = e & 4095;
    float w = (k < NDIN) ? Wx[(size_t)k * NG + col] : Wh[(size_t)(k - NDIN) * NG + col];
    float back;
    unsigned short w0 = bf_hi(w, &back);
    unsigned short w1 = bf_hi(w - back, &back);
    int g = col >> 10, j = col & 1023;
    int jb = j >> 2, jc = j & 3, n = g * 4 + jc;
    int ku = k >> 5, kr = k & 31;
    int lane = (kr >> 3) * 16 + n, j8 = kr & 7;
    size_t off = ((size_t)jb * 40 + ku) * 1024 + lane * 8 + j8;
    Wzf[off] = w0;          // plane 0 (hi)
    Wzf[off + 512] = w1;    // plane 1 (lo)
}

// x ([64][512][256]) -> A-frag order [t][ku(8)][mb(4)][lane(64)][j(8)], hi/lo
__global__ void packX_kernel(const float* __restrict__ x,
                             unsigned short* __restrict__ xf0, unsigned short* __restrict__ xf1) {
    int e = blockIdx.x * 256 + threadIdx.x;
    if (e >= NB * NT * NDIN) return;
    int k = e & 255, t = (e >> 8) & 511, m = e >> 17;
    float v = x[e];
    float back;
    unsigned short a0 = bf_hi(v, &back);
    unsigned short a1 = bf_hi(v - back, &back);
    int ku = k >> 5, kr = k & 31, mb = m >> 4;
    int lane = (kr >> 3) * 16 + (m & 15), j = kr & 7;
    size_t off = ((((size_t)t * 8 + ku) * 4 + mb) * 64 + lane) * 8 + j;
    xf0[off] = a0; xf1[off] = a1;
}

// Wo (1024 x 256) -> B-frag order [nb(16)][ku(32)][lane(64)][j(8)], hi/lo
__global__ void packWo_kernel(const float* __restrict__ Wo,
                              unsigned short* __restrict__ Wo0f, unsigned short* __restrict__ Wo1f) {
    int e = blockIdx.x * 256 + threadIdx.x;
    if (e >= NH * NDOUT) return;
    int k = e >> 8, n = e & 255;
    float w = Wo[e];
    float back;
    unsigned short w0 = bf_hi(w, &back);
    unsigned short w1 = bf_hi(w - back, &back);
    int nb = n >> 4, nl = n & 15, ku = k >> 5, kr = k & 31;
    int lane = (kr >> 3) * 16 + nl, j = kr & 7;
    size_t off = (((size_t)nb * 32 + ku) * 64 + lane) * 8 + j;
    Wo0f[off] = w0; Wo1f[off] = w1;
}

// z MFMA set for one h-ku (3 planes x 4 mb)
#define ZMFMA(S0, S1, kk) do {                                                    \
    const unsigned short* _wp = wlds + (8 + w4 + (kk)) * 1024 + lane8;            \
    short8 _Wh = *(const short8*)(_wp);                                           \
    short8 _Wl = *(const short8*)(_wp + 512);                                     \
    acc[0] = __builtin_amdgcn_mfma_f32_16x16x32_bf16(S0[0], _Wh, acc[0], 0, 0, 0);\
    acc[0] = __builtin_amdgcn_mfma_f32_16x16x32_bf16(S0[0], _Wl, acc[0], 0, 0, 0);\
    acc[0] = __builtin_amdgcn_mfma_f32_16x16x32_bf16(S1[0], _Wh, acc[0], 0, 0, 0);\
    acc[1] = __builtin_amdgcn_mfma_f32_16x16x32_bf16(S0[1], _Wh, acc[1], 0, 0, 0);\
    acc[1] = __builtin_amdgcn_mfma_f32_16x16x32_bf16(S0[1], _Wl, acc[1], 0, 0, 0);\
    acc[1] = __builtin_amdgcn_mfma_f32_16x16x32_bf16(S1[1], _Wh, acc[1], 0, 0, 0);\
    acc[2] = __builtin_amdgcn_mfma_f32_16x16x32_bf16(S0[2], _Wh, acc[2], 0, 0, 0);\
    acc[2] = __builtin_amdgcn_mfma_f32_16x16x32_bf16(S0[2], _Wl, acc[2], 0, 0, 0);\
    acc[2] = __builtin_amdgcn_mfma_f32_16x16x32_bf16(S1[2], _Wh, acc[2], 0, 0, 0);\
    acc[3] = __builtin_amdgcn_mfma_f32_16x16x32_bf16(S0[3], _Wh, acc[3], 0, 0, 0);\
    acc[3] = __builtin_amdgcn_mfma_f32_16x16x32_bf16(S0[3], _Wl, acc[3], 0, 0, 0);\
    acc[3] = __builtin_amdgcn_mfma_f32_16x16x32_bf16(S1[3], _Wh, acc[3], 0, 0, 0);\
} while (0)

// x loads for step tt into X0g/X1g (iteration-scope arrays)
#define XLOAD(tt) do {                                                            \
    const unsigned short* _xp0 = xf0 + ((size_t)(tt) * 8 + w) * 2048 + lane8;     \
    const unsigned short* _xp1 = xf1 + ((size_t)(tt) * 8 + w) * 2048 + lane8;     \
    _Pragma("unroll")                                                             \
    for (int _mb = 0; _mb < 4; ++_mb) {                                           \
        X0g[_mb] = *(const short8*)(_xp0 + _mb * 512);                            \
        X1g[_mb] = *(const short8*)(_xp1 + _mb * 512);                            \
    }                                                                             \
} while (0)

// x-partial MFMA (REPLACES acc) using preloaded X0g/X1g
#define XMFMA() do {                                                              \
    const short8 _Wh = *(const short8*)(wlds + w * 1024 + lane8);                 \
    const short8 _Wl = *(const short8*)(wlds + w * 1024 + 512 + lane8);           \
    _Pragma("unroll")                                                             \
    for (int _mb = 0; _mb < 4; ++_mb) {                                           \
        float4v _a = (float4v){0.f, 0.f, 0.f, 0.f};                               \
        _a = __builtin_amdgcn_mfma_f32_16x16x32_bf16(X0g[_mb], _Wh, _a, 0, 0, 0); \
        _a = __builtin_amdgcn_mfma_f32_16x16x32_bf16(X0g[_mb], _Wl, _a, 0, 0, 0); \
        _a = __builtin_amdgcn_mfma_f32_16x16x32_bf16(X1g[_mb], _Wh, _a, 0, 0, 0); \
        acc[_mb] = _a;                                                            \
    }                                                                             \
} while (0)

// ================= 256-block persistent kernel (fused tail) ====================
__global__ __launch_bounds__(512, 2) void persist_z256_kernel(
    const unsigned short* __restrict__ Wzf,
    const unsigned short* __restrict__ xf0, const unsigned short* __restrict__ xf1,
    const unsigned short* __restrict__ Wo0f, const unsigned short* __restrict__ Wo1f,
    unsigned short* __restrict__ hh, float* __restrict__ opart,
    const float* __restrict__ bias, const float* __restrict__ bo,
    float* __restrict__ out, unsigned* __restrict__ bar)
{
    extern __shared__ char dynlds[];
    unsigned short* wlds = (unsigned short*)dynlds;          // [40][2][64][8] = 80 KB
    float* red  = (float*)(dynlds + 81920);                  // [8][1024] z splitK slabs
    float* red2 = (float*)(dynlds + 114688);                 // [8][256] proj slabs

    const int bid = blockIdx.x, tid = threadIdx.x;
    const int lane = tid & 63, w = tid >> 6;
    const int lane8 = lane * 8, w4 = w * 4;

    // ---- one-time: W slice -> LDS (80 KB straight copy) ----
    {
        const unsigned short* src = Wzf + (size_t)bid * 40960;
        for (int i = tid; i < 5120; i += 512)
            *(short8*)(wlds + i * 8) = *(const short8*)(src + i * 8);
    }
    __syncthreads();

    // ---- gate constants (threads 0..255 own (row, col)) ----
    const int grow = tid >> 2, gjc = tid & 3;
    const int gj = bid * 4 + gjc;
    const float b_i = bias[gj], b_f = bias[NH + gj], b_g = bias[2 * NH + gj], b_o = bias[3 * NH + gj];
    const int zb = ((grow >> 4) * 64 + (((grow & 15) >> 2) * 16) + gjc) * 4 + (grow & 3);
    const int kuh = bid >> 3, krh3 = (bid & 7) >> 1, j80 = (bid & 1) * 4;
    const size_t hp = ((size_t)(kuh * 4 + (grow >> 4))) * 512
                    + (krh3 * 16 + (grow & 15)) * 8 + j80;
    float creg = 0.0f;

    // ---- proj constants: block owns tile (mbp,nbp) x K-quarter kq; wave owns 1 ku
    const int kq = bid & 3, tt0 = bid >> 2;
    const int mbp = tt0 >> 4, nbp = tt0 & 15;
    const int kup = kq * 8 + w;
    const size_t wo_off = (((size_t)nbp * 32 + kup) * 64 + lane) * 8;
    const short8 PWh = *(const short8*)(Wo0f + wo_off);
    const short8 PWl = *(const short8*)(Wo1f + wo_off);
    // proj-reduce constants (threads 256..383; 2 outputs each)
    const int prq = tid - 256;
    const int prc = prq & 15, prr = (prq >> 4) & 3, prh = prq >> 6;   // prh in {0,1}
    // outred constants (threads 384..511 on blocks <32; 4 floats each)
    const int orvalid = (bid < 32 && tid >= 384);
    const int oridx = bid * 128 + (tid - 384);               // [0,4096) when valid
    const int orm = oridx >> 6, oroc4 = (oridx & 63) * 4;

    float4v acc[4];
    short8 X0g[4], X1g[4];
    XLOAD(0); XMFMA();                                       // prologue: x(0) partial

    for (int t = 0; t <= NT + 2; ++t) {
        const unsigned short* hb0 = hh + (size_t)t * HSTEP;
        const int projA = (t >= 1 && t <= NT);

        if (t < NT) {
            // ---- poll: waves 0-5 watch 32 z-producers + 8 proj-producers;
            //      waves 6-7 watch all 256 (needed before early opart reads).
            if (w < 6) {
                const int fidx = (lane < 32) ? (w * 32 + lane)
                                             : ((kq * 8 + w) * 8 + (lane & 7));
                unsigned* f = bar + (unsigned)fidx * 4;
                for (;;) {
                    unsigned v = __hip_atomic_load(f, __ATOMIC_RELAXED,
                                                   __HIP_MEMORY_SCOPE_AGENT);
                    if (__all(v >= (unsigned)t)) break;
                }
            } else {
                unsigned* f = bar + (unsigned)lane * 4;
                for (;;) {
                    unsigned v0 = __hip_atomic_load(f,       __ATOMIC_RELAXED, __HIP_MEMORY_SCOPE_AGENT);
                    unsigned v1 = __hip_atomic_load(f + 256, __ATOMIC_RELAXED, __HIP_MEMORY_SCOPE_AGENT);
                    unsigned v2 = __hip_atomic_load(f + 512, __ATOMIC_RELAXED, __HIP_MEMORY_SCOPE_AGENT);
                    unsigned v3 = __hip_atomic_load(f + 768, __ATOMIC_RELAXED, __HIP_MEMORY_SCOPE_AGENT);
                    unsigned mn = min(min(v0, v1), min(v2, v3));
                    if (__all(mn >= (unsigned)t)) break;
                }
            }
            asm volatile("" ::: "memory");

            // ---- load window: 32 h GLDs, then ALL tail loads (counts keep the
            // counted vmcnt waits safe: extras only tighten earlier waits). ----
            short8 A0[4][4], A1[4][4];
            #pragma unroll
            for (int kk = 0; kk < 4; ++kk) {
                const unsigned short* _p = hb0 + (size_t)(w4 + kk) * 2048 + lane8;
                GLD(A0[kk][0], _p);        GLD(A0[kk][1], _p + 512);
                GLD(A0[kk][2], _p + 1024); GLD(A0[kk][3], _p + 1536);
                const unsigned short* _q = _p + 65536;
                GLD(A1[kk][0], _q);        GLD(A1[kk][1], _q + 512);
                GLD(A1[kk][2], _q + 1024); GLD(A1[kk][3], _q + 1536);
            }
            short8 PAh = {}, PAl = {};
            if (projA) {
                const unsigned short* ap = hb0 + (size_t)(kup * 4 + mbp) * 512 + lane8;
                PAh = *(const short8*)ap;
                PAl = *(const short8*)(ap + 65536);
            }
            if (t + 1 < NT) XLOAD(t + 1);
            float4v os0, os1, os2, os3;
            const int doOR = (orvalid && t >= 3);
            if (doOR) {
                const float* op = opart + (size_t)((t - 2) & 3) * 65536;
                SCLD(os0, &op[(size_t)orm * NDOUT + oroc4]);
                SCLD(os1, &op[16384 + (size_t)orm * NDOUT + oroc4]);
                SCLD(os2, &op[32768 + (size_t)orm * NDOUT + oroc4]);
                SCLD(os3, &op[49152 + (size_t)orm * NDOUT + oroc4]);
            }

            asm volatile("s_waitcnt vmcnt(24)" ::: "memory");
            __builtin_amdgcn_sched_barrier(0);
            ZMFMA(A0[0], A1[0], 0);
            asm volatile("s_waitcnt vmcnt(16)" ::: "memory");
            __builtin_amdgcn_sched_barrier(0);
            ZMFMA(A0[1], A1[1], 1);
            asm volatile("s_waitcnt vmcnt(8)" ::: "memory");
            __builtin_amdgcn_sched_barrier(0);
            ZMFMA(A0[2], A1[2], 2);
            asm volatile("s_waitcnt vmcnt(0)" ::: "memory");
            __builtin_amdgcn_sched_barrier(0);
            ZMFMA(A0[3], A1[3], 3);

            // z slabs + proj MFMA + proj slab, ONE sync
            {
                float* slab = red + w * 1024;
                #pragma unroll
                for (int mb = 0; mb < 4; ++mb)
                    *(float4v*)&slab[(mb * 64 + lane) * 4] = acc[mb];
            }
            if (projA) {
                float4v pacc = (float4v){0.f, 0.f, 0.f, 0.f};
                pacc = __builtin_amdgcn_mfma_f32_16x16x32_bf16(PAh, PWh, pacc, 0, 0, 0);
                pacc = __builtin_amdgcn_mfma_f32_16x16x32_bf16(PAh, PWl, pacc, 0, 0, 0);
                pacc = __builtin_amdgcn_mfma_f32_16x16x32_bf16(PAl, PWh, pacc, 0, 0, 0);
                *(float4v*)&red2[(w * 64 + lane) * 4] = pacc;
            }
            __syncthreads();

            // ---- parallel phase: gate | proj-reduce | outred ----
            if (tid < 256) {
                float zi = b_i, zf = b_f, zg = b_g, zo = b_o;
                #pragma unroll
                for (int ww = 0; ww < 8; ++ww) {
                    const float* s = red + ww * 1024;
                    zi += s[zb]; zf += s[zb + 16]; zg += s[zb + 32]; zo += s[zb + 48];
                }
                float iv = sigf(zi), fv = sigf(zf), gv = tanhf(zg), ov = sigf(zo);
                creg = fv * creg + iv * gv;
                float hv = ov * tanhf(creg);
                float back;
                unsigned short h0 = bf_hi(hv, &back);
                unsigned short h1 = bf_hi(hv - back, &back);
                unsigned v = (unsigned)h0 | ((unsigned)h1 << 16);
                const int base = lane & ~3;
                unsigned v0 = __shfl(v, base, 64);
                unsigned v1 = __shfl(v, base + 1, 64);
                unsigned v2 = __shfl(v, base + 2, 64);
                unsigned v3 = __shfl(v, base + 3, 64);
                if ((lane & 3) == 0) {
                    uint2v hi2, lo2;
                    hi2[0] = (v0 & 0xFFFFu) | (v1 << 16);
                    hi2[1] = (v2 & 0xFFFFu) | (v3 << 16);
                    lo2[0] = (v0 >> 16) | (v1 & 0xFFFF0000u);
                    lo2[1] = (v2 >> 16) | (v3 & 0xFFFF0000u);
                    unsigned short* hw = hh + (size_t)(t + 1) * HSTEP;
                    sc_store_dwordx2(hw + hp, hi2);
                    sc_store_dwordx2(hw + hp + 65536, lo2);
                }
            } else if (tid < 384) {
                if (projA) {
                    #pragma unroll
                    for (int h2 = 0; h2 < 2; ++h2) {
                        const int hb4 = prh + h2 * 2;
                        const int p = (hb4 * 16 + prc) * 4 + prr;
                        float s = 0.f;
                        #pragma unroll
                        for (int ww = 0; ww < 8; ++ww) s += red2[ww * 256 + p];
                        const int prow = mbp * 16 + hb4 * 4 + prr;
                        const int pcol = nbp * 16 + prc;
                        sc_store_dword(opart + (size_t)(t & 3) * 65536 + (size_t)kq * 16384
                                       + (size_t)prow * NDOUT + pcol, s);
                    }
                }
            } else if (doOR) {
                float4v bv = *(const float4v*)&bo[oroc4];
                float4v v = os0 + os1 + os2 + os3 + bv;
                float4v rr;
                rr[0] = fmaxf(v[0], 0.f); rr[1] = fmaxf(v[1], 0.f);
                rr[2] = fmaxf(v[2], 0.f); rr[3] = fmaxf(v[3], 0.f);
                *(float4v*)&out[((size_t)orm * NT + (t - 3)) * NDOUT + oroc4] = rr;
            }

            flag_arrive(bar, bid, t);

            if (t + 1 < NT) XMFMA();                         // only tail work left
        } else {
            // ---- tail iterations t = NT..NT+2 ----
            wait_full(bar, t);
            if (t == NT) {
                // cold proj(NT)
                const unsigned short* ap = hb0 + (size_t)(kup * 4 + mbp) * 512 + lane8;
                short8 PAh = *(const short8*)ap;
                short8 PAl = *(const short8*)(ap + 65536);
                float4v pacc = (float4v){0.f, 0.f, 0.f, 0.f};
                pacc = __builtin_amdgcn_mfma_f32_16x16x32_bf16(PAh, PWh, pacc, 0, 0, 0);
                pacc = __builtin_amdgcn_mfma_f32_16x16x32_bf16(PAh, PWl, pacc, 0, 0, 0);
                pacc = __builtin_amdgcn_mfma_f32_16x16x32_bf16(PAl, PWh, pacc, 0, 0, 0);
                *(float4v*)&red2[(w * 64 + lane) * 4] = pacc;
                __syncthreads();
                if (tid >= 256 && tid < 384) {
                    #pragma unroll
                    for (int h2 = 0; h2 < 2; ++h2) {
                        const int hb4 = prh + h2 * 2;
                        const int p = (hb4 * 16 + prc) * 4 + prr;
                        float s = 0.f;
                        #pragma unroll
                        for (int ww = 0; ww < 8; ++ww) s += red2[ww * 256 + p];
                        const int prow = mbp * 16 + hb4 * 4 + prr;
                        const int pcol = nbp * 16 + prc;
                        sc_store_dword(opart + (size_t)(t & 3) * 65536 + (size_t)kq * 16384
                                       + (size_t)prow * NDOUT + pcol, s);
                    }
                }
            }
            if (orvalid && t >= 3) {
                const float* op = opart + (size_t)((t - 2) & 3) * 65536;
                float4v s0, s1, s2, s3;
                LD4(s0, s1, s2, s3,
                    &op[(size_t)orm * NDOUT + oroc4],
                    &op[16384 + (size_t)orm * NDOUT + oroc4],
                    &op[32768 + (size_t)orm * NDOUT + oroc4],
                    &op[49152 + (size_t)orm * NDOUT + oroc4]);
                float4v bv = *(const float4v*)&bo[oroc4];
                float4v v = s0 + s1 + s2 + s3 + bv;
                float4v rr;
                rr[0] = fmaxf(v[0], 0.f); rr[1] = fmaxf(v[1], 0.f);
                rr[2] = fmaxf(v[2], 0.f); rr[3] = fmaxf(v[3], 0.f);
                *(float4v*)&out[((size_t)orm * NT + (t - 3)) * NDOUT + oroc4] = rr;
            }
            flag_arrive(bar, bid, t);
        }
    }
}

extern "C" void kernel_launch(void* const* d_in, const int* in_sizes, int n_in,
                              void* d_out, int out_size, void* d_ws, size_t ws_size,
                              hipStream_t stream) {
    const float* x  = (const float*)d_in[0];
    const float* Wx = (const float*)d_in[1];
    const float* Wh = (const float*)d_in[2];
    const float* b  = (const float*)d_in[3];
    const float* Wo = (const float*)d_in[4];
    const float* bo = (const float*)d_in[5];
    float* out = (float*)d_out;
    char* ws = (char*)d_ws;

    const size_t hh_bytes = (size_t)(NT + 3) * HSTEP * 2;    // 515 x 256 KB

    size_t off = 0;
    unsigned* bar = (unsigned*)(ws + off);             off += 4096;   // 256 flags @16B stride
    unsigned short* hh = (unsigned short*)(ws + off);  off += hh_bytes;
    size_t zero_floats = (4096 + (size_t)HSTEP * 2) / 4;      // bar + hh slab0
    float* opart = (float*)(ws + off);                 off += (size_t)4 * 4 * NB * NDOUT * 4;  // 1 MB ring
    unsigned short* Wzf = (unsigned short*)(ws + off); off += (size_t)1280 * 4096 * 2 * 2;     // 21 MB
    unsigned short* Wo0f = (unsigned short*)(ws + off); off += (size_t)NH * NDOUT * 2;
    unsigned short* Wo1f = (unsigned short*)(ws + off); off += (size_t)NH * NDOUT * 2;
    unsigned short* xf0 = (unsigned short*)(ws + off); off += (size_t)NB * NT * NDIN * 2;
    unsigned short* xf1 = (unsigned short*)(ws + off); off += (size_t)NB * NT * NDIN * 2;

    zero_kernel<<<(int)((zero_floats + 255) / 256), 256, 0, stream>>>((float*)ws, (int)zero_floats);
    packWz_kernel<<<(1280 * 4096 + 255) / 256, 256, 0, stream>>>(Wx, Wh, Wzf);
    packX_kernel<<<(NB * NT * NDIN + 255) / 256, 256, 0, stream>>>(x, xf0, xf1);
    packWo_kernel<<<(NH * NDOUT + 255) / 256, 256, 0, stream>>>(Wo, Wo0f, Wo1f);

    void* args[] = {(void*)&Wzf, (void*)&xf0, (void*)&xf1, (void*)&Wo0f, (void*)&Wo1f,
                    (void*)&hh, (void*)&opart, (void*)&b, (void*)&bo, (void*)&out, (void*)&bar};
    hipLaunchCooperativeKernel((void*)persist_z256_kernel, dim3(GRIDN), dim3(512),
                               args, (unsigned)LDSB, stream);
}